// Round 2
// baseline (476.132 us; speedup 1.0000x reference)
//
#include <hip/hip_runtime.h>

static constexpr int kBN   = 737280;   // B*T*V*H*W
static constexpr int kSlab = 92160;    // V*H*W
static constexpr int kNT   = 512;      // NUM_TRACKS
static constexpr int kNSeg = 4096;     // (B*T)*NUM_TRACKS
static constexpr int kChunk = 5120;    // elements per count/fill block (18 per slab, single bt)

// ---------------- count (LDS-privatized histogram) ----------------
__global__ __launch_bounds__(1024) void k_count(const int* __restrict__ gid, int* cnt) {
    __shared__ int h[kNT];
    int tid = threadIdx.x;
    if (tid < kNT) h[tid] = 0;
    __syncthreads();
    int chunk0 = blockIdx.x * kChunk;
    int bt = chunk0 / kSlab;            // chunk never straddles a slab (92160 = 18*5120)
    for (int j = tid; j < kChunk; j += 1024) {
        int id = gid[chunk0 + j];
        if (id >= 0) atomicAdd(&h[id], 1);
    }
    __syncthreads();
    if (tid < kNT) { int v = h[tid]; if (v) atomicAdd(&cnt[bt * kNT + tid], v); }
}

// ---------------- exclusive scan of 4096 counts (single block) ----------------
__global__ __launch_bounds__(1024) void k_scan(const int* __restrict__ cnt, int* offs, int* cursor) {
    __shared__ int part[1024];
    int tid = threadIdx.x;
    int b = tid * 4;
    int v0 = cnt[b], v1 = cnt[b + 1], v2 = cnt[b + 2], v3 = cnt[b + 3];
    int s01 = v0 + v1, s = s01 + v2 + v3;
    part[tid] = s;
    __syncthreads();
    for (int off = 1; off < 1024; off <<= 1) {
        int t = (tid >= off) ? part[tid - off] : 0;
        __syncthreads();
        part[tid] += t;
        __syncthreads();
    }
    int base = part[tid] - s;           // exclusive prefix of this thread's group of 4
    int o0 = base, o1 = base + v0, o2 = base + s01, o3 = base + s01 + v2;
    offs[b] = o0; offs[b + 1] = o1; offs[b + 2] = o2; offs[b + 3] = o3;
    cursor[b] = o0; cursor[b + 1] = o1; cursor[b + 2] = o2; cursor[b + 3] = o3;
}

// ---------------- fill per-segment index lists (privatized) ----------------
__global__ __launch_bounds__(1024) void k_fill(const int* __restrict__ gid, int* cursor, int* lists) {
    __shared__ int lcnt[kNT];
    __shared__ int lbase[kNT];
    int tid = threadIdx.x;
    if (tid < kNT) lcnt[tid] = 0;
    __syncthreads();
    int chunk0 = blockIdx.x * kChunk;
    int bt = chunk0 / kSlab;
    int rank[5], ids[5];
#pragma unroll
    for (int u = 0; u < 5; u++) {
        int id = gid[chunk0 + tid + u * 1024];
        ids[u] = id;
        rank[u] = (id >= 0) ? atomicAdd(&lcnt[id], 1) : 0;
    }
    __syncthreads();
    if (tid < kNT) { int c = lcnt[tid]; lbase[tid] = c ? atomicAdd(&cursor[bt * kNT + tid], c) : 0; }
    __syncthreads();
#pragma unroll
    for (int u = 0; u < 5; u++) {
        int id = ids[u];
        if (id >= 0) lists[lbase[id] + rank[u]] = chunk0 + tid + u * 1024;
    }
}

// ---------------- per-wave channel reduce helper ----------------
template<int CNT>
__device__ __forceinline__ void wreduce_store(float (&a)[17], int lane, int tb, float* totl) {
#pragma unroll
    for (int c = 0; c < CNT; c++) {
        float v = a[c];
#pragma unroll
        for (int m = 1; m < 64; m <<= 1) v += __shfl_xor(v, m, 64);
        if (lane == 0) totl[tb + c] = v;
    }
}

// ---------------- per-segment merge + fused output write ----------------
// One block per segment. Waves split the 66 channels: w0=cen/off/opac/scale/
// rot/fd/keep (out ch 0..17), w1=inst[0:16] (18..33), w2=inst[16:32] (34..49),
// w3=motion+z2 (50..65). Pass 4 loads every listed element's slice: active
// lanes accumulate (same shfl order as previous passing kernel), inactive
// lanes write the passthrough slice straight to out. Final loop broadcasts the
// merged record (sfac-adjusted) to all active rows. merged/mc1g/repg buffers
// and the full-re-read k_out are gone.
__global__ __launch_bounds__(256, 4) void k_seg(
        const int* __restrict__ lists, const int* __restrict__ offs, const int* __restrict__ cnt,
        const float* __restrict__ keep, const float* __restrict__ center,
        const float* __restrict__ offsetp, const float* __restrict__ opacity,
        const float* __restrict__ scale, const float* __restrict__ rot,
        const float* __restrict__ fd, const float* __restrict__ inst,
        const float* __restrict__ motion,
        float* __restrict__ out) {
    // XCD-chunked swizzle: 8 XCDs, 512 segments (one bt-slab) per XCD
    int s = ((blockIdx.x & 7) << 9) | (blockIdx.x >> 3);
    int n = cnt[s];
    if (n < 2) return;                  // not dup: k_rest passes through
    int base = offs[s];
    int tid = threadIdx.x;
    int lane = tid & 63;
    int wv = tid >> 6;

    __shared__ int   idxs[256];
    __shared__ float kk[256];
    __shared__ float c0s[256], c1s[256], c2s[256];
    __shared__ float e2s[256];
    __shared__ float red4[256][5];      // pad 5 -> conflict-free tree
    __shared__ float wm1[4], wm2[4];
    __shared__ int   wri[4];
    __shared__ float totl[66];
    __shared__ float mrec[66];

    // ---- pass 1: stage keep/center/idx + m1 (max, order-free) ----
    float lmax = -1e30f;
    for (int j = tid; j < n; j += 256) {
        int i = lists[base + j];
        float k = keep[i];
        float cx = center[3 * i + 0], cy = center[3 * i + 1], cz = center[3 * i + 2];
        if (j < 256) { idxs[j] = i; kk[j] = k; c0s[j] = cx; c1s[j] = cy; c2s[j] = cz; }
        lmax = fmaxf(lmax, k);
    }
#pragma unroll
    for (int m = 1; m < 64; m <<= 1) lmax = fmaxf(lmax, __shfl_xor(lmax, m, 64));
    if (lane == 0) wm1[wv] = lmax;
    __syncthreads();
    float m1 = fmaxf(fmaxf(wm1[0], wm1[1]), fmaxf(wm1[2], wm1[3]));

    // ---- pass 2: z1 + weighted center sums (order-exact vs previous kernel) ----
    float lz = 0.f, l0 = 0.f, l1 = 0.f, l2 = 0.f;
    for (int j = tid; j < n; j += 256) {
        float k, cx, cy, cz;
        if (j < 256) { k = kk[j]; cx = c0s[j]; cy = c1s[j]; cz = c2s[j]; }
        else { int i = lists[base + j]; k = keep[i];
               cx = center[3 * i + 0]; cy = center[3 * i + 1]; cz = center[3 * i + 2]; }
        float e = expf(k - m1);
        lz += e; l0 += e * cx; l1 += e * cy; l2 += e * cz;
    }
    red4[tid][0] = lz; red4[tid][1] = l0; red4[tid][2] = l1; red4[tid][3] = l2;
    __syncthreads();
    for (int o = 128; o; o >>= 1) {
        if (tid < o) {
            red4[tid][0] += red4[tid + o][0]; red4[tid][1] += red4[tid + o][1];
            red4[tid][2] += red4[tid + o][2]; red4[tid][3] += red4[tid + o][3];
        }
        __syncthreads();
    }
    float z1 = red4[0][0];
    float inv1 = 1.0f / fmaxf(z1, 1e-20f);
    float mc0 = red4[0][1] * inv1, mcy = red4[0][2] * inv1, mcz = red4[0][3] * inv1;

    // ---- pass 3: m2 over active (max, order-free); cache act flag ----
    float lm2 = -1e30f;
    for (int j = tid; j < n; j += 256) {
        float k, cx, cy, cz;
        if (j < 256) { k = kk[j]; cx = c0s[j]; cy = c1s[j]; cz = c2s[j]; }
        else { int i = lists[base + j]; k = keep[i];
               cx = center[3 * i + 0]; cy = center[3 * i + 1]; cz = center[3 * i + 2]; }
        float d0 = cx - mc0, d1 = cy - mcy, d2 = cz - mcz;
        bool act = sqrtf(d0 * d0 + d1 * d1 + d2 * d2) <= 2.0f;
        if (j < 256) e2s[j] = act ? 1.0f : 0.0f;
        if (act) lm2 = fmaxf(lm2, k);
    }
#pragma unroll
    for (int m = 1; m < 64; m <<= 1) lm2 = fmaxf(lm2, __shfl_xor(lm2, m, 64));
    if (lane == 0) wm2[wv] = lm2;
    __syncthreads();
    float m2 = fmaxf(fmaxf(wm2[0], wm2[1]), fmaxf(wm2[2], wm2[3]));

    // ---- pass 3b: e2 weights into LDS + rep (min, order-free) ----
    int lrep = 0x7fffffff;
    for (int j = tid; j < n; j += 256) {
        if (j < 256) {
            bool act = e2s[j] != 0.0f;
            float k = kk[j];
            float e = act ? expf(k - m2) : 0.0f;
            e2s[j] = e;
            if (act && k == m2) lrep = min(lrep, idxs[j]);
        } else {
            int i = lists[base + j];
            float k = keep[i];
            float cx = center[3 * i + 0], cy = center[3 * i + 1], cz = center[3 * i + 2];
            float d0 = cx - mc0, d1 = cy - mcy, d2 = cz - mcz;
            if (sqrtf(d0 * d0 + d1 * d1 + d2 * d2) <= 2.0f && k == m2) lrep = min(lrep, i);
        }
    }
#pragma unroll
    for (int m = 1; m < 64; m <<= 1) lrep = min(lrep, __shfl_xor(lrep, m, 64));
    if (lane == 0) wri[wv] = lrep;
    __syncthreads();                    // also publishes e2s to all waves
    int rep = min(min(wri[0], wri[1]), min(wri[2], wri[3]));

    // n>256 fallback: recompute weight from globals (never taken in practice)
    auto e2_glob = [&](int j, int& i) -> float {
        i = lists[base + j];
        float k = keep[i];
        float d0 = center[3 * i + 0] - mc0;
        float d1 = center[3 * i + 1] - mcy;
        float d2 = center[3 * i + 2] - mcz;
        return (sqrtf(d0 * d0 + d1 * d1 + d2 * d2) <= 2.0f) ? expf(k - m2) : 0.0f;
    };

    // ---- pass 4: register-accumulated sums + fused passthrough writes ----
    {
        float a[17];
#pragma unroll
        for (int c = 0; c < 17; c++) a[c] = 0.f;

        if (wv == 0) {
            for (int j = lane; j < n; j += 64) {
                float e, cx, cy, cz, k; int i;
                if (j < 256) { e = e2s[j]; i = idxs[j]; cx = c0s[j]; cy = c1s[j]; cz = c2s[j]; k = kk[j]; }
                else { e = e2_glob(j, i); k = keep[i];
                       cx = center[3 * i + 0]; cy = center[3 * i + 1]; cz = center[3 * i + 2]; }
                float o0 = offsetp[3 * i + 0], o1 = offsetp[3 * i + 1], o2 = offsetp[3 * i + 2];
                float op = opacity[i];
                float s0 = scale[3 * i + 0], s1 = scale[3 * i + 1], s2 = scale[3 * i + 2];
                float4 r4 = *(const float4*)(rot + 4 * i);
                float f0 = fd[3 * i + 0], f1 = fd[3 * i + 1], f2 = fd[3 * i + 2];
                if (e != 0.0f) {
                    a[0] += e * cx; a[1] += e * cy; a[2] += e * cz;
                    a[3] += e * o0; a[4] += e * o1; a[5] += e * o2;
                    a[6] += e * op;
                    a[7] += e * s0; a[8] += e * s1; a[9] += e * s2;
                    a[10] += e * r4.x; a[11] += e * r4.y; a[12] += e * r4.z; a[13] += e * r4.w;
                    a[14] += e * f0; a[15] += e * f1; a[16] += e * f2;
                } else {
                    float* o = out + (long)66 * i;
                    o[0] = cx; o[1] = cy; o[2] = cz;
                    o[3] = o0; o[4] = o1; o[5] = o2;
                    o[6] = op;
                    o[7] = s0; o[8] = s1; o[9] = s2;
                    o[10] = r4.x; o[11] = r4.y; o[12] = r4.z; o[13] = r4.w;
                    o[14] = f0; o[15] = f1; o[16] = f2;
                    o[17] = k;
                }
            }
            wreduce_store<17>(a, lane, 0, totl);
        } else if (wv == 1) {
            for (int j = lane; j < n; j += 64) {
                float e; int i;
                if (j < 256) { e = e2s[j]; i = idxs[j]; } else { e = e2_glob(j, i); }
                const float4* ip = (const float4*)(inst + 32 * i);
                float4 v0 = ip[0], v1 = ip[1], v2 = ip[2], v3 = ip[3];
                if (e != 0.0f) {
                    a[0]  += e * v0.x; a[1]  += e * v0.y; a[2]  += e * v0.z; a[3]  += e * v0.w;
                    a[4]  += e * v1.x; a[5]  += e * v1.y; a[6]  += e * v1.z; a[7]  += e * v1.w;
                    a[8]  += e * v2.x; a[9]  += e * v2.y; a[10] += e * v2.z; a[11] += e * v2.w;
                    a[12] += e * v3.x; a[13] += e * v3.y; a[14] += e * v3.z; a[15] += e * v3.w;
                } else {
                    float2* o = (float2*)(out + (long)66 * i + 18);
                    o[0] = make_float2(v0.x, v0.y); o[1] = make_float2(v0.z, v0.w);
                    o[2] = make_float2(v1.x, v1.y); o[3] = make_float2(v1.z, v1.w);
                    o[4] = make_float2(v2.x, v2.y); o[5] = make_float2(v2.z, v2.w);
                    o[6] = make_float2(v3.x, v3.y); o[7] = make_float2(v3.z, v3.w);
                }
            }
            wreduce_store<16>(a, lane, 17, totl);
        } else if (wv == 2) {
            for (int j = lane; j < n; j += 64) {
                float e; int i;
                if (j < 256) { e = e2s[j]; i = idxs[j]; } else { e = e2_glob(j, i); }
                const float4* ip = (const float4*)(inst + 32 * i) + 4;
                float4 v0 = ip[0], v1 = ip[1], v2 = ip[2], v3 = ip[3];
                if (e != 0.0f) {
                    a[0]  += e * v0.x; a[1]  += e * v0.y; a[2]  += e * v0.z; a[3]  += e * v0.w;
                    a[4]  += e * v1.x; a[5]  += e * v1.y; a[6]  += e * v1.z; a[7]  += e * v1.w;
                    a[8]  += e * v2.x; a[9]  += e * v2.y; a[10] += e * v2.z; a[11] += e * v2.w;
                    a[12] += e * v3.x; a[13] += e * v3.y; a[14] += e * v3.z; a[15] += e * v3.w;
                } else {
                    float2* o = (float2*)(out + (long)66 * i + 34);
                    o[0] = make_float2(v0.x, v0.y); o[1] = make_float2(v0.z, v0.w);
                    o[2] = make_float2(v1.x, v1.y); o[3] = make_float2(v1.z, v1.w);
                    o[4] = make_float2(v2.x, v2.y); o[5] = make_float2(v2.z, v2.w);
                    o[6] = make_float2(v3.x, v3.y); o[7] = make_float2(v3.z, v3.w);
                }
            }
            wreduce_store<16>(a, lane, 33, totl);
        } else {
            for (int j = lane; j < n; j += 64) {
                float e; int i;
                if (j < 256) { e = e2s[j]; i = idxs[j]; } else { e = e2_glob(j, i); }
                const float4* mp = (const float4*)(motion + 16 * i);
                float4 v0 = mp[0], v1 = mp[1], v2 = mp[2], v3 = mp[3];
                if (e != 0.0f) {
                    a[0]  += e * v0.x; a[1]  += e * v0.y; a[2]  += e * v0.z; a[3]  += e * v0.w;
                    a[4]  += e * v1.x; a[5]  += e * v1.y; a[6]  += e * v1.z; a[7]  += e * v1.w;
                    a[8]  += e * v2.x; a[9]  += e * v2.y; a[10] += e * v2.z; a[11] += e * v2.w;
                    a[12] += e * v3.x; a[13] += e * v3.y; a[14] += e * v3.z; a[15] += e * v3.w;
                    a[16] += e;     // z2
                } else {
                    float2* o = (float2*)(out + (long)66 * i + 50);
                    o[0] = make_float2(v0.x, v0.y); o[1] = make_float2(v0.z, v0.w);
                    o[2] = make_float2(v1.x, v1.y); o[3] = make_float2(v1.z, v1.w);
                    o[4] = make_float2(v2.x, v2.y); o[5] = make_float2(v2.z, v2.w);
                    o[6] = make_float2(v3.x, v3.y); o[7] = make_float2(v3.z, v3.w);
                }
            }
            wreduce_store<17>(a, lane, 49, totl);
        }
    }
    __syncthreads();

    // ---- finalize merged record into LDS (output channel layout) ----
    if (tid < 66) {
        float z2v = totl[65];
        float inv2 = 1.0f / fmaxf(z2v, 1e-20f);
        float v;
        if (tid < 10) v = totl[tid] * inv2;                          // cen, off, opac, scale
        else if (tid < 14) {                                         // rot (normalized)
            float q0 = totl[10] * inv2, q1 = totl[11] * inv2;
            float q2 = totl[12] * inv2, q3 = totl[13] * inv2;
            float nrm = sqrtf(q0 * q0 + q1 * q1 + q2 * q2 + q3 * q3);
            float rn = 1.0f / fmaxf(nrm, 1e-12f);
            v = (totl[tid] * inv2) * rn;
        }
        else if (tid < 17) v = totl[tid] * inv2;                     // feat_dc
        else if (tid == 17) v = m2;                                  // keep (pre-sfac)
        else v = totl[tid - 1] * inv2;                               // inst, motion
        mrec[tid] = v;
    }
    __syncthreads();

    // ---- broadcast merged record to all active rows (float2, sfac on 6/17) ----
    for (int f = tid; f < n * 33; f += 256) {
        int j = f / 33;
        int c2 = f - 33 * j;
        int i; bool act;
        if (j < 256) { act = e2s[j] != 0.0f; i = idxs[j]; }
        else { float e = e2_glob(j, i); act = e != 0.0f; }
        if (act) {
            float2 v = make_float2(mrec[2 * c2], mrec[2 * c2 + 1]);
            if (i != rep) {
                if (c2 == 3) v.x *= 0.05f;        // opacity (ch 6)
                else if (c2 == 8) v.y *= 0.05f;   // keep (ch 17)
            }
            *(float2*)(out + (long)66 * i + 2 * c2) = v;
        }
    }
}

// ---------------- residual passthrough: id<0 or non-dup segments (~0.2%) ----
__global__ __launch_bounds__(256) void k_rest(
        const int* __restrict__ gid, const int* __restrict__ cnt,
        const float* __restrict__ keep, const float* __restrict__ center,
        const float* __restrict__ offsetp, const float* __restrict__ opacity,
        const float* __restrict__ scale, const float* __restrict__ rot,
        const float* __restrict__ fd, const float* __restrict__ inst,
        const float* __restrict__ motion,
        float* __restrict__ out) {
    int i = blockIdx.x * 256 + threadIdx.x;
    int id = gid[i];
    if (id >= 0 && cnt[(i / kSlab) * kNT + id] >= 2) return;   // handled by k_seg
    float* o = out + (long)i * 66;
    o[0] = center[3 * i + 0]; o[1] = center[3 * i + 1]; o[2] = center[3 * i + 2];
#pragma unroll
    for (int c = 0; c < 3; c++) o[3 + c] = offsetp[3 * i + c];
    o[6] = opacity[i];
#pragma unroll
    for (int c = 0; c < 3; c++) o[7 + c] = scale[3 * i + c];
    float4 r4 = *(const float4*)(rot + 4 * i);
    o[10] = r4.x; o[11] = r4.y; o[12] = r4.z; o[13] = r4.w;
#pragma unroll
    for (int c = 0; c < 3; c++) o[14 + c] = fd[3 * i + c];
    o[17] = keep[i];
    const float4* ip = (const float4*)(inst + 32 * i);
#pragma unroll
    for (int q = 0; q < 8; q++) {
        float4 v = ip[q];
        o[18 + 4 * q + 0] = v.x; o[18 + 4 * q + 1] = v.y;
        o[18 + 4 * q + 2] = v.z; o[18 + 4 * q + 3] = v.w;
    }
    const float4* mp = (const float4*)(motion + 16 * i);
#pragma unroll
    for (int q = 0; q < 4; q++) {
        float4 v = mp[q];
        o[50 + 4 * q + 0] = v.x; o[50 + 4 * q + 1] = v.y;
        o[50 + 4 * q + 2] = v.z; o[50 + 4 * q + 3] = v.w;
    }
}

extern "C" void kernel_launch(void* const* d_in, const int* in_sizes, int n_in,
                              void* d_out, int out_size, void* d_ws, size_t ws_size,
                              hipStream_t stream) {
    const float* center = (const float*)d_in[0];
    const float* offsetp = (const float*)d_in[1];
    const float* opacity = (const float*)d_in[2];
    const float* scale = (const float*)d_in[3];
    const float* rot = (const float*)d_in[4];
    const float* fd = (const float*)d_in[5];
    const float* keep = (const float*)d_in[6];
    const float* inst = (const float*)d_in[7];
    const float* motion = (const float*)d_in[8];
    const int* gid = (const int*)d_in[9];
    float* out = (float*)d_out;

    // workspace layout (4-byte units)
    int* cnt    = (int*)d_ws;                      // [0, 4096)
    int* offs   = (int*)d_ws + 4096;               // [4096, 8192)
    int* cursor = (int*)d_ws + 8192;               // [8192, 12288)
    int* lists  = (int*)d_ws + 12288;              // [12288, 12288+737280)

    hipMemsetAsync(cnt, 0, (size_t)kNSeg * 4, stream);

    k_count<<<kBN / kChunk, 1024, 0, stream>>>(gid, cnt);
    k_scan<<<1, 1024, 0, stream>>>(cnt, offs, cursor);
    k_fill<<<kBN / kChunk, 1024, 0, stream>>>(gid, cursor, lists);
    k_seg<<<kNSeg, 256, 0, stream>>>(lists, offs, cnt, keep, center, offsetp, opacity,
                                     scale, rot, fd, inst, motion, out);
    k_rest<<<kBN / 256, 256, 0, stream>>>(gid, cnt, keep, center, offsetp, opacity, scale,
                                          rot, fd, inst, motion, out);
}